// Round 6
// baseline (2016.370 us; speedup 1.0000x reference)
//
#include <hip/hip_runtime.h>

// GIN forward, MI355X. Round 6:
//  - COALESCING FIX: all 64-col GEMMs LDS-staged. r5 evidence: FETCH 518MB vs 105MB
//    useful on k_gemm_out1 (thread=row float4 loads -> 16B used per 64B line, L1
//    evicted before reuse). Now: block = 128 rows x 2 col-halves, A-tile staged via
//    coalesced float4 loads (xor-swizzled, 32KB LDS), BN-affine applied at stage time,
//    both halves share one staged copy (A read once from HBM).
//  - stats butterfly epilogue unchanged (r5-verified, VGPR 40 no spill)

#define HID 64
#define LAYERS 3
#define BN_EPS 1e-5f

__device__ __forceinline__ float relu_aff(float x, float s, float t) {
    return fmaxf(fmaf(x, s, t), 0.f);
}

__device__ __forceinline__ void bn_fin(const float* __restrict__ raw, const float* __restrict__ g,
                                       const float* __restrict__ b, float invN, int c,
                                       float& s, float& t) {
    float m = raw[c] * invN;
    float v = fmaf(-m, m, raw[64 + c] * invN);
    float r = rsqrtf(v + BN_EPS);
    s = r * g[c];
    t = fmaf(-m, s, b[c]);
}

// ---------------- CSR build ----------------
__global__ void k_hist(const int* __restrict__ dst, int* __restrict__ cnt, int E) {
    int e = blockIdx.x * 256 + threadIdx.x;
    if (e < E) atomicAdd(&cnt[dst[e]], 1);
}

__global__ void k_scan1(const int* __restrict__ cnt, int* __restrict__ part, int n) {
    __shared__ int sm[256];
    int i = blockIdx.x * 256 + threadIdx.x;
    sm[threadIdx.x] = (i < n) ? cnt[i] : 0;
    __syncthreads();
    for (int s = 128; s > 0; s >>= 1) {
        if (threadIdx.x < s) sm[threadIdx.x] += sm[threadIdx.x + s];
        __syncthreads();
    }
    if (threadIdx.x == 0) part[blockIdx.x] = sm[0];
}

__global__ void k_scan2(int* part, int nb, int* row_off, int N) {
    int lane = threadIdx.x & 63, wid = threadIdx.x >> 6;
    int v = (threadIdx.x < nb) ? part[threadIdx.x] : 0;
    int incl = v;
    for (int d = 1; d < 64; d <<= 1) { int y = __shfl_up(incl, d); if (lane >= d) incl += y; }
    __shared__ int ws[8];
    if (lane == 63) ws[wid] = incl;
    __syncthreads();
    if (threadIdx.x == 0) { int a = 0; for (int w = 0; w < 8; w++) { int t = ws[w]; ws[w] = a; a += t; } }
    __syncthreads();
    int excl = incl - v + ws[wid];
    if (threadIdx.x < nb) part[threadIdx.x] = excl;
    if (threadIdx.x == nb - 1) row_off[N] = excl + v;
}

__global__ void k_scan3(const int* cnt, const int* __restrict__ part,
                        int* row_off, int* cursor, int n) {
    int i = blockIdx.x * 256 + threadIdx.x;
    int lane = threadIdx.x & 63, wid = threadIdx.x >> 6;
    int v = (i < n) ? cnt[i] : 0;
    int incl = v;
    for (int d = 1; d < 64; d <<= 1) { int y = __shfl_up(incl, d); if (lane >= d) incl += y; }
    __shared__ int ws[4];
    if (lane == 63) ws[wid] = incl;
    __syncthreads();
    if (threadIdx.x == 0) { int a = 0; for (int w = 0; w < 4; w++) { int t = ws[w]; ws[w] = a; a += t; } }
    __syncthreads();
    int excl = incl - v + ws[wid] + part[blockIdx.x];
    if (i < n) { row_off[i] = excl; cursor[i] = excl; }
}

__global__ void k_scatter(const int* __restrict__ src, const int* __restrict__ dst,
                          int* __restrict__ cursor, int* __restrict__ col, int E) {
    int e = blockIdx.x * 256 + threadIdx.x;
    if (e < E) {
        int d = dst[e];
        int p = atomicAdd(&cursor[d], 1);
        col[p] = src[e];
    }
}

// ---------------- stats butterfly: 32 cols over 64 lanes ----------------
// After reduction, even lanes hold col (lane>>1); adds into ldsS[col], ldsQ[col].
__device__ __forceinline__ void col_stats_butterfly32(const float (&acc)[32], bool valid, int lane,
                                                      float* ldsS, float* ldsQ) {
    float sv[16], qv[16];
    {
        bool hi = (lane & 32) != 0;
#pragma unroll
        for (int i = 0; i < 16; i++) {
            float vlo = valid ? acc[i] : 0.f;
            float vhi = valid ? acc[16 + i] : 0.f;
            float gs = hi ? vlo : vhi;
            float ks = hi ? vhi : vlo;
            sv[i] = ks + __shfl_xor(gs, 32);
            float qlo = vlo * vlo, qhi = vhi * vhi;
            float gq = hi ? qlo : qhi;
            float kq = hi ? qhi : qlo;
            qv[i] = kq + __shfl_xor(gq, 32);
        }
    }
#pragma unroll
    for (int d = 16; d >= 2; d >>= 1) {
        bool hi = (lane & d) != 0;
        const int half = d >> 1;
#pragma unroll
        for (int i = 0; i < 16; i++) {
            if (i < half) {
                float gs = hi ? sv[i] : sv[i + half];
                float ks = hi ? sv[i + half] : sv[i];
                sv[i] = ks + __shfl_xor(gs, d);
                float gq = hi ? qv[i] : qv[i + half];
                float kq = hi ? qv[i + half] : qv[i];
                qv[i] = kq + __shfl_xor(gq, d);
            }
        }
    }
    sv[0] += __shfl_xor(sv[0], 1);
    qv[0] += __shfl_xor(qv[0], 1);
    if ((lane & 1) == 0) {
        int colj = lane >> 1;
        atomicAdd(&ldsS[colj], sv[0]);
        atomicAdd(&ldsQ[colj], qv[0]);
    }
}

// ---------------- LDS-staged GEMM: C[n x 64] = act(A[n x 64]) @ W[64 x 64] + bias ----
// block = 256 threads = 128 rows x 2 col-halves. A staged coalesced+swizzled in 32KB LDS,
// affine applied at stage. acc[32]/thread.
template <bool AFF, bool STATS>
__global__ __launch_bounds__(256) void k_gemm_lds(const float* __restrict__ A,
                                                  const float* __restrict__ rawIn, const float* __restrict__ g,
                                                  const float* __restrict__ b, float invN,
                                                  const float* __restrict__ W, const float* __restrict__ bias,
                                                  float* __restrict__ C, float* __restrict__ rawOut, int n) {
    __shared__ float lA[128 * 64];   // 32 KB, f4-swizzled: chunk j of row r at f4 pos r*16+(j^(r&15))
    __shared__ float ldsr[128];      // [0..63] col sums, [64..127] col sumsq
    const int tf = (threadIdx.x & 15) * 4;  // this thread's staged feature base (const across iters)
    float sA[4], tA[4];
    if (AFF) {
#pragma unroll
        for (int u = 0; u < 4; u++) bn_fin(rawIn, g, b, invN, tf + u, sA[u], tA[u]);
    }
    if (STATS && threadIdx.x < 128) ldsr[threadIdx.x] = 0.f;

    const size_t maxf4 = (size_t)n * 16 - 1;
    const size_t basef4 = (size_t)blockIdx.x * 128 * 16;
#pragma unroll
    for (int it = 0; it < 8; it++) {
        int L = it * 256 + threadIdx.x;
        size_t gidx = basef4 + L;
        if (gidx > maxf4) gidx = maxf4;
        float4 v = ((const float4*)A)[gidx];
        if (AFF) {
            v.x = relu_aff(v.x, sA[0], tA[0]);
            v.y = relu_aff(v.y, sA[1], tA[1]);
            v.z = relu_aff(v.z, sA[2], tA[2]);
            v.w = relu_aff(v.w, sA[3], tA[3]);
        }
        int r = L >> 4, j = L & 15;
        ((float4*)lA)[r * 16 + (j ^ (r & 15))] = v;
    }
    __syncthreads();

    const int rl = threadIdx.x & 127;
    const int half = threadIdx.x >> 7;
    const int row = blockIdx.x * 128 + rl;
    const bool valid = row < n;

    float acc[32];
#pragma unroll
    for (int j = 0; j < 32; j++) acc[j] = bias[half * 32 + j];
    const float* Wh = W + half * 32;
#pragma unroll
    for (int kk = 0; kk < 16; kk++) {
        float4 av = ((const float4*)lA)[rl * 16 + (kk ^ (rl & 15))];
        float a[4] = {av.x, av.y, av.z, av.w};
#pragma unroll
        for (int u = 0; u < 4; u++) {
            int k = kk * 4 + u;
#pragma unroll
            for (int j = 0; j < 32; j++) acc[j] = fmaf(a[u], Wh[k * HID + j], acc[j]);
        }
    }
    if (valid) {
        float4* c4 = (float4*)(C + (size_t)row * HID + half * 32);
#pragma unroll
        for (int j = 0; j < 8; j++)
            c4[j] = make_float4(acc[4 * j], acc[4 * j + 1], acc[4 * j + 2], acc[4 * j + 3]);
    }
    if constexpr (STATS) {
        int lane = threadIdx.x & 63;
        col_stats_butterfly32(acc, valid, lane, ldsr + half * 32, ldsr + 64 + half * 32);
        __syncthreads();
        if (threadIdx.x < 128) atomicAdd(&rawOut[threadIdx.x], ldsr[threadIdx.x]);
    }
}

// concat GEMM: C = [h0|h1|h2|h3] @ W[256 x 64] + bias; parts staged sequentially through
// one 32KB LDS buffer with double affine applied at stage.
__global__ __launch_bounds__(256) void k_gemm_out1(const float* __restrict__ B0, const float* __restrict__ B1,
                                                   const float* __restrict__ B2, const float* __restrict__ B3,
                                                   const float* __restrict__ raw0,
                                                   const float* __restrict__ g_in, const float* __restrict__ be_in,
                                                   const float* __restrict__ rawS2,
                                                   const float* __restrict__ g2, const float* __restrict__ be2,
                                                   const float* __restrict__ rawSP,
                                                   const float* __restrict__ g_post, const float* __restrict__ be_post,
                                                   float invN,
                                                   const float* __restrict__ W, const float* __restrict__ bias,
                                                   float* __restrict__ C, float* __restrict__ rawOut, int n) {
    __shared__ float lA[128 * 64];
    __shared__ float ldsr[128];
    const int tf = (threadIdx.x & 15) * 4;
    if (threadIdx.x < 128) ldsr[threadIdx.x] = 0.f;

    const int rl = threadIdx.x & 127;
    const int half = threadIdx.x >> 7;
    const int row = blockIdx.x * 128 + rl;
    const bool valid = row < n;
    const size_t maxf4 = (size_t)n * 16 - 1;
    const size_t basef4 = (size_t)blockIdx.x * 128 * 16;

    float acc[32];
#pragma unroll
    for (int j = 0; j < 32; j++) acc[j] = bias[half * 32 + j];
    const float* bufs[4] = {B0, B1, B2, B3};

#pragma unroll
    for (int pp = 0; pp < 4; pp++) {
        // per-part double-affine coeffs for this thread's 4 staged features
        float s2[4], t2[4], sp[4], tp[4];
#pragma unroll
        for (int u = 0; u < 4; u++) {
            int c = tf + u;
            if (pp == 0) {
                bn_fin(raw0, g_in, be_in, invN, c, s2[u], t2[u]);
                sp[u] = 1.f; tp[u] = 0.f;
            } else {
                int i = pp - 1;
                bn_fin(rawS2 + (size_t)i * 3 * 128, g2 + i * HID, be2 + i * HID, invN, c, s2[u], t2[u]);
                bn_fin(rawSP + (size_t)i * 3 * 128, g_post + i * HID, be_post + i * HID, invN, c, sp[u], tp[u]);
            }
        }
        __syncthreads();  // previous part's reads (and ldsr init) complete before overwrite
        const float* Bp = bufs[pp];
#pragma unroll
        for (int it = 0; it < 8; it++) {
            int L = it * 256 + threadIdx.x;
            size_t gidx = basef4 + L;
            if (gidx > maxf4) gidx = maxf4;
            float4 v = ((const float4*)Bp)[gidx];
            v.x = relu_aff(relu_aff(v.x, s2[0], t2[0]), sp[0], tp[0]);
            v.y = relu_aff(relu_aff(v.y, s2[1], t2[1]), sp[1], tp[1]);
            v.z = relu_aff(relu_aff(v.z, s2[2], t2[2]), sp[2], tp[2]);
            v.w = relu_aff(relu_aff(v.w, s2[3], t2[3]), sp[3], tp[3]);
            int r = L >> 4, j = L & 15;
            ((float4*)lA)[r * 16 + (j ^ (r & 15))] = v;
        }
        __syncthreads();
        const float* Wp = W + pp * HID * HID + half * 32;
#pragma unroll
        for (int kk = 0; kk < 16; kk++) {
            float4 av = ((const float4*)lA)[rl * 16 + (kk ^ (rl & 15))];
            float a[4] = {av.x, av.y, av.z, av.w};
#pragma unroll
            for (int u = 0; u < 4; u++) {
                int k = kk * 4 + u;
#pragma unroll
                for (int j = 0; j < 32; j++) acc[j] = fmaf(a[u], Wp[k * HID + j], acc[j]);
            }
        }
    }
    if (valid) {
        float4* c4 = (float4*)(C + (size_t)row * HID + half * 32);
#pragma unroll
        for (int j = 0; j < 8; j++)
            c4[j] = make_float4(acc[4 * j], acc[4 * j + 1], acc[4 * j + 2], acc[4 * j + 3]);
    }
    int lane = threadIdx.x & 63;
    col_stats_butterfly32(acc, valid, lane, ldsr + half * 32, ldsr + 64 + half * 32);
    __syncthreads();
    if (threadIdx.x < 128) atomicAdd(&rawOut[threadIdx.x], ldsr[threadIdx.x]);
}

// final small GEMM: C[n x 10] = act(A[n x 64]) @ W[64 x 10] + bias. 128 rows x 2 col-groups.
__global__ __launch_bounds__(256) void k_gemm_small(const float* __restrict__ A,
                                                    const float* __restrict__ rawIn, const float* __restrict__ g,
                                                    const float* __restrict__ b, float invN,
                                                    const float* __restrict__ W, const float* __restrict__ bias,
                                                    float* __restrict__ C, int n) {
    __shared__ float lA[128 * 64];
    const int tf = (threadIdx.x & 15) * 4;
    float sA[4], tA[4];
#pragma unroll
    for (int u = 0; u < 4; u++) bn_fin(rawIn, g, b, invN, tf + u, sA[u], tA[u]);

    const size_t maxf4 = (size_t)n * 16 - 1;
    const size_t basef4 = (size_t)blockIdx.x * 128 * 16;
#pragma unroll
    for (int it = 0; it < 8; it++) {
        int L = it * 256 + threadIdx.x;
        size_t gidx = basef4 + L;
        if (gidx > maxf4) gidx = maxf4;
        float4 v = ((const float4*)A)[gidx];
        v.x = relu_aff(v.x, sA[0], tA[0]);
        v.y = relu_aff(v.y, sA[1], tA[1]);
        v.z = relu_aff(v.z, sA[2], tA[2]);
        v.w = relu_aff(v.w, sA[3], tA[3]);
        int r = L >> 4, j = L & 15;
        ((float4*)lA)[r * 16 + (j ^ (r & 15))] = v;
    }
    __syncthreads();

    const int rl = threadIdx.x & 127;
    const int cg = threadIdx.x >> 7;  // 0: cols 0..4, 1: cols 5..9
    const int row = blockIdx.x * 128 + rl;
    if (row >= n) return;
    float acc[5];
#pragma unroll
    for (int j = 0; j < 5; j++) acc[j] = bias[cg * 5 + j];
#pragma unroll
    for (int kk = 0; kk < 16; kk++) {
        float4 av = ((const float4*)lA)[rl * 16 + (kk ^ (rl & 15))];
        float a[4] = {av.x, av.y, av.z, av.w};
#pragma unroll
        for (int u = 0; u < 4; u++) {
            int k = kk * 4 + u;
#pragma unroll
            for (int j = 0; j < 5; j++) acc[j] = fmaf(a[u], W[k * 10 + cg * 5 + j], acc[j]);
        }
    }
    float* c = C + (size_t)row * 10 + cg * 5;
#pragma unroll
    for (int j = 0; j < 5; j++) c[j] = acc[j];
}

// ---------------- aggregation: o = (1+eps)*act(h) + sum act(h[src]) ----------------
template <bool DBL>
__global__ __launch_bounds__(256) void k_agg(const float* __restrict__ hb,
                                             const float* __restrict__ rawA, const float* __restrict__ gA,
                                             const float* __restrict__ bA,
                                             const float* __restrict__ rawB, const float* __restrict__ gB,
                                             const float* __restrict__ bB, float invN,
                                             const int* __restrict__ row_off, const int* __restrict__ col,
                                             const float* __restrict__ epsp, int li,
                                             float* __restrict__ o, int n) {
    int wid = threadIdx.x >> 6, lane = threadIdx.x & 63;
    int node = blockIdx.x * 4 + wid;
    if (node >= n) return;
    float sA, tA, sB = 0.f, tB = 0.f;
    bn_fin(rawA, gA, bA, invN, lane, sA, tA);
    if (DBL) bn_fin(rawB, gB, bB, invN, lane, sB, tB);
#define ACT(v) (DBL ? relu_aff(relu_aff((v), sA, tA), sB, tB) : relu_aff((v), sA, tA))
    float ope = 1.f + epsp[li];
    float acc = ope * ACT(hb[(size_t)node * HID + lane]);
    int e = row_off[node], b1 = row_off[node + 1];

    while (e + 8 <= b1) {
        int i0 = col[e], i1 = col[e + 1], i2 = col[e + 2], i3 = col[e + 3];
        int i4 = col[e + 4], i5 = col[e + 5], i6 = col[e + 6], i7 = col[e + 7];
        float v0 = hb[(size_t)i0 * HID + lane], v1 = hb[(size_t)i1 * HID + lane];
        float v2 = hb[(size_t)i2 * HID + lane], v3 = hb[(size_t)i3 * HID + lane];
        float v4 = hb[(size_t)i4 * HID + lane], v5 = hb[(size_t)i5 * HID + lane];
        float v6 = hb[(size_t)i6 * HID + lane], v7 = hb[(size_t)i7 * HID + lane];
        acc += ACT(v0) + ACT(v1) + ACT(v2) + ACT(v3);
        acc += ACT(v4) + ACT(v5) + ACT(v6) + ACT(v7);
        e += 8;
    }
    if (e + 4 <= b1) {
        int i0 = col[e], i1 = col[e + 1], i2 = col[e + 2], i3 = col[e + 3];
        float v0 = hb[(size_t)i0 * HID + lane], v1 = hb[(size_t)i1 * HID + lane];
        float v2 = hb[(size_t)i2 * HID + lane], v3 = hb[(size_t)i3 * HID + lane];
        acc += ACT(v0) + ACT(v1) + ACT(v2) + ACT(v3);
        e += 4;
    }
    if (e + 2 <= b1) {
        int i0 = col[e], i1 = col[e + 1];
        float v0 = hb[(size_t)i0 * HID + lane], v1 = hb[(size_t)i1 * HID + lane];
        acc += ACT(v0) + ACT(v1);
        e += 2;
    }
    if (e < b1) acc += ACT(hb[(size_t)col[e] * HID + lane]);
#undef ACT
    o[(size_t)node * HID + lane] = acc;
}

// read-only: stats of relu_aff(X; affine from rawIn,g,b) -> rawOut
__global__ __launch_bounds__(256) void k_poststats(const float* __restrict__ X,
                                                   const float* __restrict__ rawIn,
                                                   const float* __restrict__ g, const float* __restrict__ b,
                                                   float invN,
                                                   float* __restrict__ rawOut, long long n64) {
    long long stride = (long long)gridDim.x * 256;
    long long i0 = (long long)blockIdx.x * 256 + threadIdx.x;
    int col = threadIdx.x & 63;
    float sA, tA;
    bn_fin(rawIn, g, b, invN, col, sA, tA);
    float s = 0.f, q = 0.f;
    for (long long i = i0; i < n64; i += stride) {
        float v = relu_aff(X[i], sA, tA);
        s += v; q = fmaf(v, v, q);
    }
    __shared__ float ls[256], lq[256];
    ls[threadIdx.x] = s; lq[threadIdx.x] = q;
    __syncthreads();
    if (threadIdx.x < 64) {
        s = ls[threadIdx.x] + ls[threadIdx.x + 64] + ls[threadIdx.x + 128] + ls[threadIdx.x + 192];
        q = lq[threadIdx.x] + lq[threadIdx.x + 64] + lq[threadIdx.x + 128] + lq[threadIdx.x + 192];
        atomicAdd(&rawOut[col], s);
        atomicAdd(&rawOut[64 + col], q);
    }
}

extern "C" void kernel_launch(void* const* d_in, const int* in_sizes, int n_in,
                              void* d_out, int out_size, void* d_ws, size_t ws_size,
                              hipStream_t stream) {
    const float* x = (const float*)d_in[0];
    const int* ei = (const int*)d_in[1];
    const float* W_in = (const float*)d_in[2];
    const float* b_in = (const float*)d_in[3];
    const float* g_in = (const float*)d_in[4];
    const float* be_in = (const float*)d_in[5];
    const float* epsp = (const float*)d_in[6];
    const float* W1 = (const float*)d_in[7];
    const float* b1 = (const float*)d_in[8];
    const float* g1 = (const float*)d_in[9];
    const float* be1 = (const float*)d_in[10];
    const float* W2 = (const float*)d_in[11];
    const float* b2 = (const float*)d_in[12];
    const float* g2 = (const float*)d_in[13];
    const float* be2 = (const float*)d_in[14];
    const float* g_post = (const float*)d_in[15];
    const float* be_post = (const float*)d_in[16];
    const float* W_out1 = (const float*)d_in[17];
    const float* b_out1 = (const float*)d_in[18];
    const float* g_out = (const float*)d_in[19];
    const float* be_out = (const float*)d_in[20];
    const float* W_out2 = (const float*)d_in[21];
    const float* b_out2 = (const float*)d_in[22];

    const int N = in_sizes[0] / HID;
    const int E = in_sizes[1] / 2;
    const int* srcp = ei;
    const int* dstp = ei + E;

    size_t NODE = (size_t)N * HID;
    float* f = (float*)d_ws;
    float* pre0 = f;                 // stage-0 pre-BN (kept for concat)
    float* z0 = f + NODE;            // layer i pre-BN2 z (kept for concat)
    float* z1 = f + 2 * NODE;
    float* z2 = f + 3 * NODE;
    float* o = f + 4 * NODE;         // aggregation output
    float* p = f + 5 * NODE;         // gemm1 output / head pre-BN (reused)
    int* rc = (int*)(f + 6 * NODE);  // counts -> row offsets, N+1
    int* cursor = rc + (N + 1);
    int* col = cursor + N;           // E
    int* part = col + E;             // scan partials, <=512
    float* raw = (float*)(part + 512);  // 11 stages x {sum[64], sumsq[64]}

    size_t need = (size_t)(6 * NODE) * 4 + ((size_t)(N + 1) + N + E + 512) * 4 + (size_t)11 * 128 * 4;
    if (ws_size < need) return;  // fail loudly (output stays poisoned)

    float invN = 1.0f / (float)N;
    int nb = (N + 255) / 256;
    int eb = (E + 255) / 256;
    int gb128 = (N + 127) / 128;

    hipMemsetAsync(rc, 0, (size_t)(N + 1) * sizeof(int), stream);
    hipMemsetAsync(raw, 0, (size_t)11 * 128 * sizeof(float), stream);

    k_hist<<<eb, 256, 0, stream>>>(dstp, rc, E);
    k_scan1<<<nb, 256, 0, stream>>>(rc, part, N);
    k_scan2<<<1, 512, 0, stream>>>(part, nb, rc, N);
    k_scan3<<<nb, 256, 0, stream>>>(rc, part, rc, cursor, N);
    k_scatter<<<eb, 256, 0, stream>>>(srcp, dstp, cursor, col, E);

    // input projection + fused stats -> raw[0]
    k_gemm_lds<false, true><<<gb128, 256, 0, stream>>>(x, nullptr, nullptr, nullptr, invN,
                                                       W_in, b_in, pre0, raw, N);

    float* zb[3] = {z0, z1, z2};
    for (int i = 0; i < LAYERS; i++) {
        int s1 = 1 + 3 * i, s2 = 2 + 3 * i, sp = 3 + 3 * i;
        const float* hb = (i == 0) ? pre0 : zb[i - 1];
        if (i == 0) {
            k_agg<false><<<(N + 3) / 4, 256, 0, stream>>>(hb, raw, g_in, be_in,
                                                          nullptr, nullptr, nullptr, invN,
                                                          rc, col, epsp, i, o, N);
        } else {
            int ps2 = 2 + 3 * (i - 1), psp = 3 + 3 * (i - 1);
            k_agg<true><<<(N + 3) / 4, 256, 0, stream>>>(hb,
                                                         raw + (size_t)ps2 * 128, g2 + (i - 1) * HID, be2 + (i - 1) * HID,
                                                         raw + (size_t)psp * 128, g_post + (i - 1) * HID, be_post + (i - 1) * HID,
                                                         invN, rc, col, epsp, i, o, N);
        }
        k_gemm_lds<false, true><<<gb128, 256, 0, stream>>>(o, nullptr, nullptr, nullptr, invN,
                                                           W1 + (size_t)i * HID * HID, b1 + i * HID,
                                                           p, raw + (size_t)s1 * 128, N);
        k_gemm_lds<true, true><<<gb128, 256, 0, stream>>>(p, raw + (size_t)s1 * 128, g1 + i * HID, be1 + i * HID, invN,
                                                          W2 + (size_t)i * HID * HID, b2 + i * HID,
                                                          zb[i], raw + (size_t)s2 * 128, N);
        k_poststats<<<512, 256, 0, stream>>>(zb[i], raw + (size_t)s2 * 128, g2 + i * HID, be2 + i * HID, invN,
                                             raw + (size_t)sp * 128, (long long)NODE);
    }

    // head: concat (double affines at stage) -> 256x64 GEMM + stats -> 64x10 GEMM
    k_gemm_out1<<<gb128, 256, 0, stream>>>(pre0, z0, z1, z2,
                                           raw, g_in, be_in,
                                           raw + 2 * 128, g2, be2,
                                           raw + 3 * 128, g_post, be_post,
                                           invN, W_out1, b_out1, p, raw + 10 * 128, N);
    k_gemm_small<<<gb128, 256, 0, stream>>>(p, raw + 10 * 128, g_out, be_out, invN,
                                            W_out2, b_out2, (float*)d_out, N);
}

// Round 7
// 1448.592 us; speedup vs baseline: 1.3920x; 1.3920x over previous
//
#include <hip/hip_runtime.h>

// GIN forward, MI355X. Round 7:
//  - GEMM rebuild after r6 spill catastrophe (VGPR=256, 501MB scratch writes):
//    64 rows x 4 col-groups, acc[16]/thread, LDS stride-65 staging (2-way banks = free),
//    W/bias via readfirstlane(cg) scalar loads, #pragma unroll 1 on multi-part loop.
//  - CSR build: 2-pass binned sort (bin = dst>>7). Pass A appends (src,dst) to per-bin
//    buckets (sequential-per-bin -> full write lines; r2 scatter was 105MB for 6.4MB useful).
//    Pass B: block/bin, LDS hist+scan, emits row_off + col in an L2-hot window.
//    Bucket aliases the 'o' buffer (used only before k_agg).

#define HID 64
#define LAYERS 3
#define BN_EPS 1e-5f
#define BINB 7
#define MAXBIN 1024
#define RPB 64
#define LSTR 65

__device__ __forceinline__ float relu_aff(float x, float s, float t) {
    return fmaxf(fmaf(x, s, t), 0.f);
}

__device__ __forceinline__ void bn_fin(const float* __restrict__ raw, const float* __restrict__ g,
                                       const float* __restrict__ b, float invN, int c,
                                       float& s, float& t) {
    float m = raw[c] * invN;
    float v = fmaf(-m, m, raw[64 + c] * invN);
    float r = rsqrtf(v + BN_EPS);
    s = r * g[c];
    t = fmaf(-m, s, b[c]);
}

// ---------------- binned CSR build ----------------
__global__ __launch_bounds__(256) void k_binhist(const int* __restrict__ dst, int* __restrict__ binCnt,
                                                 int E, int nbin) {
    __shared__ int h[MAXBIN];
    for (int i = threadIdx.x; i < nbin; i += 256) h[i] = 0;
    __syncthreads();
    int stride = gridDim.x * 256;
    for (int e = blockIdx.x * 256 + threadIdx.x; e < E; e += stride)
        atomicAdd(&h[dst[e] >> BINB], 1);
    __syncthreads();
    for (int i = threadIdx.x; i < nbin; i += 256) {
        int v = h[i];
        if (v) atomicAdd(&binCnt[i], v);
    }
}

// 1 block, 1024 threads: exclusive scan of binCnt[0..nbin) -> binOff, binCur; row_off[N]=E
__global__ __launch_bounds__(1024) void k_binscan(const int* __restrict__ binCnt, int* __restrict__ binOff,
                                                  int* __restrict__ binCur, int nbin, int E,
                                                  int* __restrict__ row_off, int N) {
    int tid = threadIdx.x, lane = tid & 63, wid = tid >> 6;
    int v = (tid < nbin) ? binCnt[tid] : 0;
    int incl = v;
    for (int d = 1; d < 64; d <<= 1) { int y = __shfl_up(incl, d); if (lane >= d) incl += y; }
    __shared__ int ws[16];
    if (lane == 63) ws[wid] = incl;
    __syncthreads();
    if (tid == 0) { int a = 0; for (int w = 0; w < 16; w++) { int t = ws[w]; ws[w] = a; a += t; } }
    __syncthreads();
    int excl = incl - v + ws[wid];
    if (tid <= nbin) binOff[tid] = excl;
    if (tid < nbin) binCur[tid] = excl;
    if (tid == 0) { row_off[N] = E; binOff[nbin] = E; }
}

__global__ __launch_bounds__(256) void k_passA(const int* __restrict__ src, const int* __restrict__ dst,
                                               int* __restrict__ binCur, int2* __restrict__ buck, int E) {
    int e = blockIdx.x * 256 + threadIdx.x;
    if (e < E) {
        int d = dst[e];
        int p = atomicAdd(&binCur[d >> BINB], 1);
        buck[p] = make_int2(src[e], d);
    }
}

// block = bin: LDS hist of 128 local dsts, scan, emit row_off and scatter col.
__global__ __launch_bounds__(256) void k_passB(const int2* __restrict__ buck, const int* __restrict__ binOff,
                                               int* __restrict__ row_off, int* __restrict__ colv, int N) {
    __shared__ int h[128], cur[128];
    __shared__ int ws2[4];
    int bin = blockIdx.x;
    int base = binOff[bin], end = binOff[bin + 1];
    int tid = threadIdx.x;
    if (tid < 128) h[tid] = 0;
    __syncthreads();
    for (int i = base + tid; i < end; i += 256)
        atomicAdd(&h[buck[i].y & 127], 1);
    __syncthreads();
    int lane = tid & 63, wid = tid >> 6;
    int v = (tid < 128) ? h[tid] : 0;
    int incl = v;
    for (int d = 1; d < 64; d <<= 1) { int y = __shfl_up(incl, d); if (lane >= d) incl += y; }
    if (lane == 63) ws2[wid] = incl;
    __syncthreads();
    if (tid == 0) { int a = 0; for (int w = 0; w < 2; w++) { int t = ws2[w]; ws2[w] = a; a += t; } }
    __syncthreads();
    int excl = incl - v + ((wid < 2) ? ws2[wid] : 0);
    if (tid < 128) {
        cur[tid] = excl;
        int d = (bin << BINB) + tid;
        if (d < N) row_off[d] = base + excl;
    }
    __syncthreads();
    for (int i = base + tid; i < end; i += 256) {
        int2 sd = buck[i];
        int lp = atomicAdd(&cur[sd.y & 127], 1);
        colv[base + lp] = sd.x;
    }
}

// ---------------- stats: 16 cols over 64 lanes, reduce-scatter butterfly ----------------
// Result: lanes with (lane&3)==0 hold col (lane>>2)&15; direct store (one wave owns slice).
__device__ __forceinline__ void col_stats16(const float (&acc)[16], bool valid, int lane,
                                            float* __restrict__ ldsS, float* __restrict__ ldsQ) {
    float sv[8], qv[8];
    {
        bool hi = (lane & 32) != 0;
#pragma unroll
        for (int i = 0; i < 8; i++) {
            float vlo = valid ? acc[i] : 0.f;
            float vhi = valid ? acc[8 + i] : 0.f;
            float gs = hi ? vlo : vhi, ks = hi ? vhi : vlo;
            sv[i] = ks + __shfl_xor(gs, 32);
            float qlo = vlo * vlo, qhi = vhi * vhi;
            float gq = hi ? qlo : qhi, kq = hi ? qhi : qlo;
            qv[i] = kq + __shfl_xor(gq, 32);
        }
    }
#pragma unroll
    for (int d = 16; d >= 4; d >>= 1) {
        bool hi = (lane & d) != 0;
        const int half = d >> 2;  // 4, 2, 1
#pragma unroll
        for (int i = 0; i < 8; i++) {
            if (i < half) {
                float gs = hi ? sv[i] : sv[i + half], ks = hi ? sv[i + half] : sv[i];
                sv[i] = ks + __shfl_xor(gs, d);
                float gq = hi ? qv[i] : qv[i + half], kq = hi ? qv[i + half] : qv[i];
                qv[i] = kq + __shfl_xor(gq, d);
            }
        }
    }
    sv[0] += __shfl_xor(sv[0], 2); qv[0] += __shfl_xor(qv[0], 2);
    sv[0] += __shfl_xor(sv[0], 1); qv[0] += __shfl_xor(qv[0], 1);
    if ((lane & 3) == 0) {
        int c = (lane >> 2) & 15;
        ldsS[c] = sv[0];
        ldsQ[c] = qv[0];
    }
}

// ---------------- GEMM: C[n x 64] = act(A[n x 64]) @ W[64 x 64] + bias ----------------
// 64 rows/block, 4 col-groups of 16. acc[16]/thread. LDS stride-65.
template <bool AFF, bool STATS>
__global__ __launch_bounds__(256) void k_gemm_v7(const float* __restrict__ A,
                                                 const float* __restrict__ rawIn, const float* __restrict__ g,
                                                 const float* __restrict__ b, float invN,
                                                 const float* __restrict__ W, const float* __restrict__ bias,
                                                 float* __restrict__ C, float* __restrict__ rawOut, int n) {
    __shared__ float lA[RPB * LSTR];
    __shared__ float ldsr[128];
    const int tid = threadIdx.x;
    const int tf = (tid & 15) * 4;  // staged feature base, constant across iterations
    float sA[4], tA[4];
    if (AFF) {
#pragma unroll
        for (int u = 0; u < 4; u++) bn_fin(rawIn, g, b, invN, tf + u, sA[u], tA[u]);
    }
    const size_t maxf4 = (size_t)n * 16 - 1;
    const size_t basef4 = (size_t)blockIdx.x * RPB * 16;
#pragma unroll
    for (int it = 0; it < 4; it++) {
        int L = it * 256 + tid;
        size_t gidx = basef4 + L;
        if (gidx > maxf4) gidx = maxf4;
        float4 v = ((const float4*)A)[gidx];
        if (AFF) {
            v.x = relu_aff(v.x, sA[0], tA[0]);
            v.y = relu_aff(v.y, sA[1], tA[1]);
            v.z = relu_aff(v.z, sA[2], tA[2]);
            v.w = relu_aff(v.w, sA[3], tA[3]);
        }
        float* dp = &lA[(L >> 4) * LSTR + (L & 15) * 4];
        dp[0] = v.x; dp[1] = v.y; dp[2] = v.z; dp[3] = v.w;
    }
    __syncthreads();

    const int rl = tid & 63;
    const int cg = __builtin_amdgcn_readfirstlane(tid >> 6);
    const int row = blockIdx.x * RPB + rl;
    const bool valid = row < n;
    float acc[16];
#pragma unroll
    for (int j = 0; j < 16; j++) acc[j] = bias[cg * 16 + j];
    const float* Wc = W + cg * 16;
    const float* ar = &lA[rl * LSTR];
#pragma unroll 4
    for (int k = 0; k < 64; k++) {
        float a = ar[k];
#pragma unroll
        for (int j = 0; j < 16; j++) acc[j] = fmaf(a, Wc[k * HID + j], acc[j]);
    }
    if (valid) {
        float4* c4 = (float4*)(C + (size_t)row * HID + cg * 16);
#pragma unroll
        for (int j = 0; j < 4; j++)
            c4[j] = make_float4(acc[4 * j], acc[4 * j + 1], acc[4 * j + 2], acc[4 * j + 3]);
    }
    if constexpr (STATS) {
        col_stats16(acc, valid, rl, ldsr + cg * 16, ldsr + 64 + cg * 16);
        __syncthreads();
        if (tid < 128) atomicAdd(&rawOut[tid], ldsr[tid]);
    }
}

// concat GEMM: C = [h0|h1|h2|h3] @ W[256 x 64] + bias, parts staged sequentially (unroll 1).
__global__ __launch_bounds__(256) void k_gemm_out1(const float* __restrict__ B0, const float* __restrict__ B1,
                                                   const float* __restrict__ B2, const float* __restrict__ B3,
                                                   const float* __restrict__ raw0,
                                                   const float* __restrict__ g_in, const float* __restrict__ be_in,
                                                   const float* __restrict__ rawS2,
                                                   const float* __restrict__ g2, const float* __restrict__ be2,
                                                   const float* __restrict__ rawSP,
                                                   const float* __restrict__ g_post, const float* __restrict__ be_post,
                                                   float invN,
                                                   const float* __restrict__ W, const float* __restrict__ bias,
                                                   float* __restrict__ C, float* __restrict__ rawOut, int n) {
    __shared__ float lA[RPB * LSTR];
    __shared__ float ldsr[128];
    const int tid = threadIdx.x;
    const int tf = (tid & 15) * 4;
    const int rl = tid & 63;
    const int cg = __builtin_amdgcn_readfirstlane(tid >> 6);
    const int row = blockIdx.x * RPB + rl;
    const bool valid = row < n;
    const size_t maxf4 = (size_t)n * 16 - 1;
    const size_t basef4 = (size_t)blockIdx.x * RPB * 16;
    float acc[16];
#pragma unroll
    for (int j = 0; j < 16; j++) acc[j] = bias[cg * 16 + j];
    const float* bufs[4] = {B0, B1, B2, B3};
#pragma unroll 1
    for (int pp = 0; pp < 4; pp++) {
        float s2[4], t2[4], sp[4], tp[4];
#pragma unroll
        for (int u = 0; u < 4; u++) {
            int c = tf + u;
            if (pp == 0) {
                bn_fin(raw0, g_in, be_in, invN, c, s2[u], t2[u]);
                sp[u] = 1.f; tp[u] = 0.f;
            } else {
                int i = pp - 1;
                bn_fin(rawS2 + (size_t)i * 3 * 128, g2 + i * HID, be2 + i * HID, invN, c, s2[u], t2[u]);
                bn_fin(rawSP + (size_t)i * 3 * 128, g_post + i * HID, be_post + i * HID, invN, c, sp[u], tp[u]);
            }
        }
        __syncthreads();  // previous part's compute reads done before overwrite
        const float* Bp = bufs[pp];
#pragma unroll
        for (int it = 0; it < 4; it++) {
            int L = it * 256 + tid;
            size_t gidx = basef4 + L;
            if (gidx > maxf4) gidx = maxf4;
            float4 v = ((const float4*)Bp)[gidx];
            v.x = relu_aff(relu_aff(v.x, s2[0], t2[0]), sp[0], tp[0]);
            v.y = relu_aff(relu_aff(v.y, s2[1], t2[1]), sp[1], tp[1]);
            v.z = relu_aff(relu_aff(v.z, s2[2], t2[2]), sp[2], tp[2]);
            v.w = relu_aff(relu_aff(v.w, s2[3], t2[3]), sp[3], tp[3]);
            float* dp = &lA[(L >> 4) * LSTR + (L & 15) * 4];
            dp[0] = v.x; dp[1] = v.y; dp[2] = v.z; dp[3] = v.w;
        }
        __syncthreads();
        const float* Wp = W + pp * HID * HID + cg * 16;
        const float* ar = &lA[rl * LSTR];
#pragma unroll 4
        for (int k = 0; k < 64; k++) {
            float a = ar[k];
#pragma unroll
            for (int j = 0; j < 16; j++) acc[j] = fmaf(a, Wp[k * HID + j], acc[j]);
        }
    }
    if (valid) {
        float4* c4 = (float4*)(C + (size_t)row * HID + cg * 16);
#pragma unroll
        for (int j = 0; j < 4; j++)
            c4[j] = make_float4(acc[4 * j], acc[4 * j + 1], acc[4 * j + 2], acc[4 * j + 3]);
    }
    col_stats16(acc, valid, rl, ldsr + cg * 16, ldsr + 64 + cg * 16);
    __syncthreads();
    if (tid < 128) atomicAdd(&rawOut[tid], ldsr[tid]);
}

// final GEMM: C[n x 10] = act(A[n x 64]) @ W[64 x 10] + bias (cg 0,1 compute 5 cols each)
__global__ __launch_bounds__(256) void k_gemm_small(const float* __restrict__ A,
                                                    const float* __restrict__ rawIn, const float* __restrict__ g,
                                                    const float* __restrict__ b, float invN,
                                                    const float* __restrict__ W, const float* __restrict__ bias,
                                                    float* __restrict__ C, int n) {
    __shared__ float lA[RPB * LSTR];
    const int tid = threadIdx.x;
    const int tf = (tid & 15) * 4;
    float sA[4], tA[4];
#pragma unroll
    for (int u = 0; u < 4; u++) bn_fin(rawIn, g, b, invN, tf + u, sA[u], tA[u]);
    const size_t maxf4 = (size_t)n * 16 - 1;
    const size_t basef4 = (size_t)blockIdx.x * RPB * 16;
#pragma unroll
    for (int it = 0; it < 4; it++) {
        int L = it * 256 + tid;
        size_t gidx = basef4 + L;
        if (gidx > maxf4) gidx = maxf4;
        float4 v = ((const float4*)A)[gidx];
        v.x = relu_aff(v.x, sA[0], tA[0]);
        v.y = relu_aff(v.y, sA[1], tA[1]);
        v.z = relu_aff(v.z, sA[2], tA[2]);
        v.w = relu_aff(v.w, sA[3], tA[3]);
        float* dp = &lA[(L >> 4) * LSTR + (L & 15) * 4];
        dp[0] = v.x; dp[1] = v.y; dp[2] = v.z; dp[3] = v.w;
    }
    __syncthreads();
    const int rl = tid & 63;
    const int cg = __builtin_amdgcn_readfirstlane(tid >> 6);
    const int row = blockIdx.x * RPB + rl;
    if (cg >= 2 || row >= n) return;
    float acc[5];
#pragma unroll
    for (int j = 0; j < 5; j++) acc[j] = bias[cg * 5 + j];
    const float* ar = &lA[rl * LSTR];
#pragma unroll 4
    for (int k = 0; k < 64; k++) {
        float a = ar[k];
#pragma unroll
        for (int j = 0; j < 5; j++) acc[j] = fmaf(a, W[k * 10 + cg * 5 + j], acc[j]);
    }
    float* c = C + (size_t)row * 10 + cg * 5;
#pragma unroll
    for (int j = 0; j < 5; j++) c[j] = acc[j];
}

// ---------------- aggregation: o = (1+eps)*act(h) + sum act(h[src]) ----------------
template <bool DBL>
__global__ __launch_bounds__(256) void k_agg(const float* __restrict__ hb,
                                             const float* __restrict__ rawA, const float* __restrict__ gA,
                                             const float* __restrict__ bA,
                                             const float* __restrict__ rawB, const float* __restrict__ gB,
                                             const float* __restrict__ bB, float invN,
                                             const int* __restrict__ row_off, const int* __restrict__ col,
                                             const float* __restrict__ epsp, int li,
                                             float* __restrict__ o, int n) {
    int wid = threadIdx.x >> 6, lane = threadIdx.x & 63;
    int node = blockIdx.x * 4 + wid;
    if (node >= n) return;
    float sA, tA, sB = 0.f, tB = 0.f;
    bn_fin(rawA, gA, bA, invN, lane, sA, tA);
    if (DBL) bn_fin(rawB, gB, bB, invN, lane, sB, tB);
#define ACT(v) (DBL ? relu_aff(relu_aff((v), sA, tA), sB, tB) : relu_aff((v), sA, tA))
    float ope = 1.f + epsp[li];
    float acc = ope * ACT(hb[(size_t)node * HID + lane]);
    int e = row_off[node], b1 = row_off[node + 1];
    while (e + 8 <= b1) {
        int i0 = col[e], i1 = col[e + 1], i2 = col[e + 2], i3 = col[e + 3];
        int i4 = col[e + 4], i5 = col[e + 5], i6 = col[e + 6], i7 = col[e + 7];
        float v0 = hb[(size_t)i0 * HID + lane], v1 = hb[(size_t)i1 * HID + lane];
        float v2 = hb[(size_t)i2 * HID + lane], v3 = hb[(size_t)i3 * HID + lane];
        float v4 = hb[(size_t)i4 * HID + lane], v5 = hb[(size_t)i5 * HID + lane];
        float v6 = hb[(size_t)i6 * HID + lane], v7 = hb[(size_t)i7 * HID + lane];
        acc += ACT(v0) + ACT(v1) + ACT(v2) + ACT(v3);
        acc += ACT(v4) + ACT(v5) + ACT(v6) + ACT(v7);
        e += 8;
    }
    if (e + 4 <= b1) {
        int i0 = col[e], i1 = col[e + 1], i2 = col[e + 2], i3 = col[e + 3];
        float v0 = hb[(size_t)i0 * HID + lane], v1 = hb[(size_t)i1 * HID + lane];
        float v2 = hb[(size_t)i2 * HID + lane], v3 = hb[(size_t)i3 * HID + lane];
        acc += ACT(v0) + ACT(v1) + ACT(v2) + ACT(v3);
        e += 4;
    }
    if (e + 2 <= b1) {
        int i0 = col[e], i1 = col[e + 1];
        float v0 = hb[(size_t)i0 * HID + lane], v1 = hb[(size_t)i1 * HID + lane];
        acc += ACT(v0) + ACT(v1);
        e += 2;
    }
    if (e < b1) acc += ACT(hb[(size_t)col[e] * HID + lane]);
#undef ACT
    o[(size_t)node * HID + lane] = acc;
}

// read-only: stats of relu_aff(X; affine from rawIn,g,b) -> rawOut
__global__ __launch_bounds__(256) void k_poststats(const float* __restrict__ X,
                                                   const float* __restrict__ rawIn,
                                                   const float* __restrict__ g, const float* __restrict__ b,
                                                   float invN,
                                                   float* __restrict__ rawOut, long long n64) {
    long long stride = (long long)gridDim.x * 256;
    long long i0 = (long long)blockIdx.x * 256 + threadIdx.x;
    int col = threadIdx.x & 63;
    float sA, tA;
    bn_fin(rawIn, g, b, invN, col, sA, tA);
    float s = 0.f, q = 0.f;
    for (long long i = i0; i < n64; i += stride) {
        float v = relu_aff(X[i], sA, tA);
        s += v; q = fmaf(v, v, q);
    }
    __shared__ float ls[256], lq[256];
    ls[threadIdx.x] = s; lq[threadIdx.x] = q;
    __syncthreads();
    if (threadIdx.x < 64) {
        s = ls[threadIdx.x] + ls[threadIdx.x + 64] + ls[threadIdx.x + 128] + ls[threadIdx.x + 192];
        q = lq[threadIdx.x] + lq[threadIdx.x + 64] + lq[threadIdx.x + 128] + lq[threadIdx.x + 192];
        atomicAdd(&rawOut[col], s);
        atomicAdd(&rawOut[64 + col], q);
    }
}

extern "C" void kernel_launch(void* const* d_in, const int* in_sizes, int n_in,
                              void* d_out, int out_size, void* d_ws, size_t ws_size,
                              hipStream_t stream) {
    const float* x = (const float*)d_in[0];
    const int* ei = (const int*)d_in[1];
    const float* W_in = (const float*)d_in[2];
    const float* b_in = (const float*)d_in[3];
    const float* g_in = (const float*)d_in[4];
    const float* be_in = (const float*)d_in[5];
    const float* epsp = (const float*)d_in[6];
    const float* W1 = (const float*)d_in[7];
    const float* b1 = (const float*)d_in[8];
    const float* g1 = (const float*)d_in[9];
    const float* be1 = (const float*)d_in[10];
    const float* W2 = (const float*)d_in[11];
    const float* b2 = (const float*)d_in[12];
    const float* g2 = (const float*)d_in[13];
    const float* be2 = (const float*)d_in[14];
    const float* g_post = (const float*)d_in[15];
    const float* be_post = (const float*)d_in[16];
    const float* W_out1 = (const float*)d_in[17];
    const float* b_out1 = (const float*)d_in[18];
    const float* g_out = (const float*)d_in[19];
    const float* be_out = (const float*)d_in[20];
    const float* W_out2 = (const float*)d_in[21];
    const float* b_out2 = (const float*)d_in[22];

    const int N = in_sizes[0] / HID;
    const int E = in_sizes[1] / 2;
    const int* srcp = ei;
    const int* dstp = ei + E;
    const int nbin = (N + 127) >> BINB;
    if (nbin > MAXBIN) return;  // fail loudly

    size_t NODE = (size_t)N * HID;
    float* f = (float*)d_ws;
    float* pre0 = f;                 // stage-0 pre-BN (kept for concat)
    float* z0 = f + NODE;
    float* z1 = f + 2 * NODE;
    float* z2 = f + 3 * NODE;
    float* o = f + 4 * NODE;         // aggregation output; ALSO aliases bucket (pre-agg only)
    float* p = f + 5 * NODE;
    int2* buck = (int2*)o;           // E int2 = 12.8MB < NODE*4 = 25.6MB
    int* rc = (int*)(f + 6 * NODE);  // row_off, N+1
    int* col = rc + (N + 1);         // E
    int* binCnt = col + E;           // MAXBIN
    float* raw = (float*)(binCnt + MAXBIN);  // 11*128, adjacent to binCnt for single memset
    int* binOff = (int*)(raw + 11 * 128);    // MAXBIN+1
    int* binCur = binOff + (MAXBIN + 1);     // MAXBIN

    size_t need = (size_t)(6 * NODE) * 4 +
                  ((size_t)(N + 1) + E + MAXBIN + 11 * 128 + (MAXBIN + 1) + MAXBIN) * 4;
    if (ws_size < need) return;

    float invN = 1.0f / (float)N;
    int eb = (E + 255) / 256;
    int gb64 = (N + RPB - 1) / RPB;

    hipMemsetAsync(binCnt, 0, (size_t)(MAXBIN + 11 * 128) * sizeof(int), stream);

    k_binhist<<<1024, 256, 0, stream>>>(dstp, binCnt, E, nbin);
    k_binscan<<<1, 1024, 0, stream>>>(binCnt, binOff, binCur, nbin, E, rc, N);
    k_passA<<<eb, 256, 0, stream>>>(srcp, dstp, binCur, buck, E);
    k_passB<<<nbin, 256, 0, stream>>>(buck, binOff, rc, col, N);

    // input projection + fused stats -> raw[0]
    k_gemm_v7<false, true><<<gb64, 256, 0, stream>>>(x, nullptr, nullptr, nullptr, invN,
                                                     W_in, b_in, pre0, raw, N);

    float* zb[3] = {z0, z1, z2};
    for (int i = 0; i < LAYERS; i++) {
        int s1 = 1 + 3 * i, s2 = 2 + 3 * i, sp = 3 + 3 * i;
        const float* hb = (i == 0) ? pre0 : zb[i - 1];
        if (i == 0) {
            k_agg<false><<<(N + 3) / 4, 256, 0, stream>>>(hb, raw, g_in, be_in,
                                                          nullptr, nullptr, nullptr, invN,
                                                          rc, col, epsp, i, o, N);
        } else {
            int ps2 = 2 + 3 * (i - 1), psp = 3 + 3 * (i - 1);
            k_agg<true><<<(N + 3) / 4, 256, 0, stream>>>(hb,
                                                         raw + (size_t)ps2 * 128, g2 + (i - 1) * HID, be2 + (i - 1) * HID,
                                                         raw + (size_t)psp * 128, g_post + (i - 1) * HID, be_post + (i - 1) * HID,
                                                         invN, rc, col, epsp, i, o, N);
        }
        k_gemm_v7<false, true><<<gb64, 256, 0, stream>>>(o, nullptr, nullptr, nullptr, invN,
                                                         W1 + (size_t)i * HID * HID, b1 + i * HID,
                                                         p, raw + (size_t)s1 * 128, N);
        k_gemm_v7<true, true><<<gb64, 256, 0, stream>>>(p, raw + (size_t)s1 * 128, g1 + i * HID, be1 + i * HID, invN,
                                                        W2 + (size_t)i * HID * HID, b2 + i * HID,
                                                        zb[i], raw + (size_t)s2 * 128, N);
        k_poststats<<<512, 256, 0, stream>>>(zb[i], raw + (size_t)s2 * 128, g2 + i * HID, be2 + i * HID, invN,
                                             raw + (size_t)sp * 128, (long long)NODE);
    }

    // head: concat (double affines at stage) -> 256x64 GEMM + stats -> 64x10 GEMM
    k_gemm_out1<<<gb64, 256, 0, stream>>>(pre0, z0, z1, z2,
                                          raw, g_in, be_in,
                                          raw + 2 * 128, g2, be2,
                                          raw + 3 * 128, g_post, be_post,
                                          invN, W_out1, b_out1, p, raw + 10 * 128, N);
    k_gemm_small<<<gb64, 256, 0, stream>>>(p, raw + 10 * 128, g_out, be_out, invN,
                                           W_out2, b_out2, (float*)d_out, N);
}